// Round 2
// baseline (671.391 us; speedup 1.0000x reference)
//
#include <hip/hip_runtime.h>

// Problem constants: B=2, S=2048, E=1024, H=16, DH=64. All fp32 in/out.
// Pipeline:
//   1) convert q,k,v,Wq,Wk,Wv,Wo fp32->bf16              (1 launch)
//   2) Q = q @ Wq^T + bq  (bf16 NT-GEMM, 128x128 tile)   (3 launches)
//   3) V^T reshape [b][h][d][s] for PV B-fragments       (1 launch)
//   4) fused attention with cross-head logit mixing      (1 launch, k-split x2)
//      S'_g = sum_h M~[g,h] * (Q_h K_h^T), M~ = (I+Wc)*(log2e/8); bc dropped
//      (constant along k => softmax-invariant). exp2-domain online softmax.
//      v3: k-split 2 (2 blocks/CU co-resident, grid 512, VGPR<=64),
//      swapped mix-MFMA so softmax rows are lane-local (2 shfls not 16,
//      1 scalar m/l state, 0-shfl P pack), f32 partial O + (m,l) out.
//   5) merge k-halves -> Obuf bf16                       (1 launch)
//   6) out = O @ Wo^T + bo, fp32 to d_out                (1 launch)
// Workspace: 0..56MB as before; Op0 @56MB (16MB, f32); Mm @72MB; Ll @72.5MB
// (total 73MB). Op1 lives in d_out (dead until final GEMM).

typedef __attribute__((ext_vector_type(8))) short bf16x8_t;   // 8 bf16 (4 VGPRs)
typedef __attribute__((ext_vector_type(4))) short bf16x4_t;   // 4 bf16 (2 VGPRs)
typedef __attribute__((ext_vector_type(4))) float f32x4_t;    // MFMA accumulator

__device__ inline unsigned short f2bf(float f) {
  unsigned u = __builtin_bit_cast(unsigned, f);
  u += 0x7fffu + ((u >> 16) & 1u);          // round-to-nearest-even
  return (unsigned short)(u >> 16);
}

struct ConvArgs {
  const float* src[7];
  unsigned short* dst[7];
  int n[7];
};

__global__ __launch_bounds__(256) void convert_f32_bf16(ConvArgs a) {
  const int which = blockIdx.y;
  const int i = (blockIdx.x * 256 + threadIdx.x) * 8;
  if (i >= a.n[which]) return;
  const float* s = a.src[which] + i;
  f32x4_t x0 = *(const f32x4_t*)(s);
  f32x4_t x1 = *(const f32x4_t*)(s + 4);
  bf16x8_t o;
#pragma unroll
  for (int j = 0; j < 4; j++) o[j] = (short)f2bf(x0[j]);
#pragma unroll
  for (int j = 0; j < 4; j++) o[4 + j] = (short)f2bf(x1[j]);
  *(bf16x8_t*)(a.dst[which] + i) = o;
}

// C[m][n] = sum_k A[m][k] * Bt[n][k] + bias[n].  M,N,K multiples of 128/128/32.
// 256 threads = 4 waves in 2x2; wave tile 64x64 = 4x4 frags of 16x16; BK=32.
__global__ __launch_bounds__(256) void gemm_bt(
    const unsigned short* __restrict__ A, const unsigned short* __restrict__ Bt,
    const float* __restrict__ bias, void* __restrict__ C,
    int M, int N, int K, int c_is_f32)
{
  __shared__ unsigned short As[128 * 32];
  __shared__ unsigned short Bs[128 * 32];
  const int t = threadIdx.x;
  const int l = t & 63;
  const int w = t >> 6;
  const int quad = l >> 4, n16 = l & 15;
  const int wm = (w & 1) * 64, wn = (w >> 1) * 64;
  const long m0 = (long)blockIdx.x * 128, n0 = (long)blockIdx.y * 128;

  f32x4_t acc[4][4] = {};

  // staging: thread t covers tile row t/4 (+64 on round 1), cols (t%4)*8..+7
  const unsigned short* gA = A + (m0 + (t >> 2)) * (long)K + (t & 3) * 8;
  const unsigned short* gB = Bt + (n0 + (t >> 2)) * (long)K + (t & 3) * 8;
  const long rowskip = 64l * K;

  for (int kt = 0; kt < K; kt += 32) {
    bf16x8_t ra0 = *(const bf16x8_t*)(gA + kt);
    bf16x8_t ra1 = *(const bf16x8_t*)(gA + kt + rowskip);
    bf16x8_t rb0 = *(const bf16x8_t*)(gB + kt);
    bf16x8_t rb1 = *(const bf16x8_t*)(gB + kt + rowskip);
    __syncthreads();                       // protect LDS from prior iter reads
    *(bf16x8_t*)&As[t * 8] = ra0;          // elem (t>>2)*32 + (t&3)*8 == t*8
    *(bf16x8_t*)&As[2048 + t * 8] = ra1;
    *(bf16x8_t*)&Bs[t * 8] = rb0;
    *(bf16x8_t*)&Bs[2048 + t * 8] = rb1;
    __syncthreads();                       // staging visible
    bf16x8_t af[4], bfr[4];
#pragma unroll
    for (int i = 0; i < 4; i++) {
      af[i]  = *(const bf16x8_t*)&As[(wm + i * 16 + n16) * 32 + quad * 8];
      bfr[i] = *(const bf16x8_t*)&Bs[(wn + i * 16 + n16) * 32 + quad * 8];
    }
#pragma unroll
    for (int mi = 0; mi < 4; mi++)
#pragma unroll
      for (int ni = 0; ni < 4; ni++)
        acc[mi][ni] = __builtin_amdgcn_mfma_f32_16x16x32_bf16(af[mi], bfr[ni], acc[mi][ni], 0, 0, 0);
  }

#pragma unroll
  for (int ni = 0; ni < 4; ni++) {
    const long n = n0 + wn + ni * 16 + n16;
    const float bv = bias[n];
#pragma unroll
    for (int mi = 0; mi < 4; mi++) {
#pragma unroll
      for (int r = 0; r < 4; r++) {
        const long m = m0 + wm + mi * 16 + quad * 4 + r;  // D: row=(l>>4)*4+reg, col=l&15
        const float v = acc[mi][ni][r] + bv;
        if (c_is_f32) ((float*)C)[m * N + n] = v;
        else ((unsigned short*)C)[m * N + n] = f2bf(v);
      }
    }
  }
}

// V [b][s][h*64+d] -> VT [b][h][d][s]
__global__ __launch_bounds__(256) void transpose_v(
    const unsigned short* __restrict__ V, unsigned short* __restrict__ VT)
{
  __shared__ unsigned short tile[64][72];   // +8 pad
  const int t = threadIdx.x;
  const int s0 = blockIdx.x * 64, h = blockIdx.y, b = blockIdx.z;
#pragma unroll
  for (int r = 0; r < 2; r++) {
    const int elem = r * 2048 + t * 8;
    const int s = elem >> 6, d = elem & 63;
    *(bf16x8_t*)&tile[s][d] =
        *(const bf16x8_t*)&V[(size_t)(b * 2048 + s0 + s) * 1024 + h * 64 + d];
  }
  __syncthreads();
#pragma unroll
  for (int r = 0; r < 2; r++) {
    const int elem = r * 2048 + t * 8;
    const int d = elem >> 6, sl = elem & 63;
    bf16x8_t o;
#pragma unroll
    for (int j = 0; j < 8; j++) o[j] = (short)tile[sl + j][d];
    *(bf16x8_t*)&VT[((size_t)(b * 16 + h) * 64 + d) * 2048 + s0 + sl] = o;
  }
}

// Fused attention v3. Grid 512 (XCD-decoded, k-split 2). 1024 threads = 16
// waves; 2 blocks/CU co-resident (launch_bounds(1024,8) -> VGPR<=64).
// Wave g: QK^T + PV head g; mix via swapped MFMA puts softmax row
// (h=n16, q=g) lane-local: keys kc*16+quad*4+r in regs, replicated m/l state
// across the 4 quad-lanes (2 shfls per reduce). Writes f32 partial O + (m,l).
__global__ __launch_bounds__(1024, 8) void attention_fused(
    const unsigned short* __restrict__ Qb, const unsigned short* __restrict__ Kb,
    const unsigned short* __restrict__ VT, const float* __restrict__ Wc,
    float* __restrict__ Op0, float* __restrict__ Op1,
    float* __restrict__ Mm, float* __restrict__ Ll)
{
  __shared__ unsigned short sraw[512 * 36];   // [col=q*32+k][slot 0..31(+4)] 36864 B
  __shared__ unsigned short pbuf2[16 * 580];  // [h]{q*36 + k}                18560 B
  __shared__ float alphabuf[16 * 17];         // [h][q], stride 17 (conflict-free)
  __shared__ unsigned short mmat[256];        // M~[g_out][h] row-major

  const int t = threadIdx.x;
  const int g = t >> 6, l = t & 63;
  const int quad = l >> 4, n16 = l & 15;

  // XCD decode: id&7 = XCD; batch pinned to an XCD half; kb interleaved
  const int id = blockIdx.x;
  const int xcd = id & 7;
  const int b = xcd >> 2;
  const int rem = id >> 3;                   // 0..63
  const int kb = rem & 1;
  const int qb = (xcd & 3) * 32 + (rem >> 1);
  const int q0 = qb * 16;
  const int k0 = kb * 1024;

  // zero sraw once: swapped-mix A-operand reads the never-written bit4-flipped
  // slot region for h>=16; 0 * (zero mfrag) must be 0, not NaN.
  for (int i = t; i < 512 * 36; i += 1024) sraw[i] = 0;
  if (t < 256) {
    // M~ = (I + Wc) * (log2e / 8): exp2-domain logits (v_exp_f32 is 2^x)
    const float v = ((((t >> 4) == (t & 15)) ? 1.0f : 0.0f) + Wc[t]) * 0.1803368801111204f;
    mmat[t] = f2bf(v);
  }
  __syncthreads();

  // mix B-frag: B[k=h=quad*8+j][n=g_out=n16]; zero for h>=16
  bf16x8_t mfrag;
  if (quad < 2) mfrag = *(const bf16x8_t*)&mmat[n16 * 16 + quad * 8];
  else { bf16x8_t z = {0, 0, 0, 0, 0, 0, 0, 0}; mfrag = z; }
  const int c7 = g >> 2;                     // (col>>7) for this wave's mix chunks

  // Q A-frags: A[m=q=n16][k=d]
  bf16x8_t qf[2];
#pragma unroll
  for (int dr = 0; dr < 2; dr++)
    qf[dr] = *(const bf16x8_t*)&Qb[(size_t)(b * 2048 + q0 + n16) * 1024 + g * 64 + dr * 32 + quad * 8];

  const int slot = g ^ (quad << 3);          // sraw h-slot (writer quad == col>>7)
  const unsigned short* kptr = Kb + (size_t)(b * 2048 + k0 + n16) * 1024 + g * 64 + quad * 8;
  const unsigned short* vptr = VT + ((size_t)(b * 16 + g) * 64 + n16) * 2048 + k0 + quad * 8;

  bf16x8_t kf[2][2], vf[4];
  auto load_kf = [&](int kt) {
#pragma unroll
    for (int kc = 0; kc < 2; kc++)
#pragma unroll
      for (int dr = 0; dr < 2; dr++)
        kf[kc][dr] = *(const bf16x8_t*)(kptr + (size_t)(kt + kc * 16) * 1024 + dr * 32);
  };
  auto load_vf = [&](int kt) {
#pragma unroll
    for (int dc = 0; dc < 4; dc++)
      vf[dc] = *(const bf16x8_t*)(vptr + (size_t)dc * 16 * 2048 + kt);
  };
  auto qk_stage = [&]() {
    f32x4_t sf[2] = {};
#pragma unroll
    for (int kc = 0; kc < 2; kc++)
#pragma unroll
      for (int dr = 0; dr < 2; dr++)
        sf[kc] = __builtin_amdgcn_mfma_f32_16x16x32_bf16(qf[dr], kf[kc][dr], sf[kc], 0, 0, 0);
    // D: row=q=quad*4+r, col=key=kc*16+n16 -> sraw[col=q*32+k][slot]
#pragma unroll
    for (int kc = 0; kc < 2; kc++)
#pragma unroll
      for (int r = 0; r < 4; r++)
        sraw[((quad * 4 + r) * 32 + kc * 16 + n16) * 36 + slot] = f2bf(sf[kc][r]);
  };

  load_kf(0);
  qk_stage();
  __syncthreads();                            // B1(0)

  f32x4_t o[4] = {};
  float m_run = -1e30f, l_run = 0.0f;

  for (int it = 0; it < 32; ++it) {
    const int kt = it * 32;
    load_vf(kt);                              // consumed at PV (crosses B2)

    // ---- head mix (swapped): D[key][g_out] = Sraw^T(32keys x 32h) @ M~ ----
    f32x4_t mixd[2];
#pragma unroll
    for (int c2 = 0; c2 < 2; c2++) {
      const int c = g * 2 + c2;               // cols [32g+16c2, +16): q=g
      const unsigned short* sp = &sraw[(c * 16 + n16) * 36 + ((quad ^ c7) << 3)];
      bf16x4_t lo = *(const bf16x4_t*)sp;     // A[m=key=n16][k=h=quad*8+j]
      bf16x4_t hi = *(const bf16x4_t*)(sp + 4);
      bf16x8_t aa = {lo[0], lo[1], lo[2], lo[3], hi[0], hi[1], hi[2], hi[3]};
      f32x4_t z = {};
      mixd[c2] = __builtin_amdgcn_mfma_f32_16x16x32_bf16(aa, mfrag, z, 0, 0, 0);
    }
    // lane holds S'[h=n16][q=g][key = c2*16 + quad*4 + r] (log2 domain)

    // ---- lane-local online softmax (row h=n16,q=g; state replicated/quad) ----
    float mx = fmaxf(fmaxf(fmaxf(mixd[0][0], mixd[0][1]), fmaxf(mixd[0][2], mixd[0][3])),
                     fmaxf(fmaxf(mixd[1][0], mixd[1][1]), fmaxf(mixd[1][2], mixd[1][3])));
    mx = fmaxf(mx, __shfl_xor(mx, 16));
    mx = fmaxf(mx, __shfl_xor(mx, 32));
    const float mnew = fmaxf(m_run, mx);
    const float alpha = exp2f(m_run - mnew);
    m_run = mnew;
    float p[2][4];
    float lsum = 0.0f;
#pragma unroll
    for (int c2 = 0; c2 < 2; c2++)
#pragma unroll
      for (int r = 0; r < 4; r++) {
        p[c2][r] = exp2f(mixd[c2][r] - mnew);
        lsum += p[c2][r];
      }
    l_run = l_run * alpha + lsum;             // lane-partial l; quad-reduce at end

    // ---- pack P pairs in-register (keys are reg-adjacent), write pbuf2 ----
    const int pbase = n16 * 580 + g * 36 + quad * 4;
#pragma unroll
    for (int c2 = 0; c2 < 2; c2++)
#pragma unroll
      for (int rp = 0; rp < 2; rp++) {
        unsigned pk;
        asm volatile("v_cvt_pk_bf16_f32 %0, %1, %2"
                     : "=v"(pk) : "v"(p[c2][2 * rp]), "v"(p[c2][2 * rp + 1]));
        *(unsigned*)&pbuf2[pbase + c2 * 16 + 2 * rp] = pk;
      }
    if (quad == 0) alphabuf[n16 * 17 + g] = alpha;
    __syncthreads();                          // B2: pbuf2/alpha ready; sraw reads done

    if (it < 31) load_kf(kt + 32);            // issue under rescale+PV, used at qk_stage

    // ---- O rescale + PV ----
#pragma unroll
    for (int r = 0; r < 4; r++) {
      const float ar = alphabuf[g * 17 + quad * 4 + r];
#pragma unroll
      for (int dc = 0; dc < 4; dc++) o[dc][r] *= ar;
    }
    const unsigned short* pp = &pbuf2[g * 580 + n16 * 36 + quad * 8];
    bf16x4_t plo = *(const bf16x4_t*)pp;
    bf16x4_t phi = *(const bf16x4_t*)(pp + 4);
    bf16x8_t pf = {plo[0], plo[1], plo[2], plo[3], phi[0], phi[1], phi[2], phi[3]};
#pragma unroll
    for (int dc = 0; dc < 4; dc++)
      o[dc] = __builtin_amdgcn_mfma_f32_16x16x32_bf16(pf, vf[dc], o[dc], 0, 0, 0);

    if (it < 31) {
      qk_stage();                             // QK(t+1) with prefetched kf
      __syncthreads();                        // B1: sraw(t+1) ready; pbuf2 reads done
    }
  }

  // ---- epilogue: quad-reduce l, write (m,l) + unnormalized f32 partial O ----
  l_run += __shfl_xor(l_run, 16);
  l_run += __shfl_xor(l_run, 32);
  if (quad == 0) {
    const size_t mi = ((size_t)(kb * 2 + b) * 16 + n16) * 2048 + q0 + g;
    Mm[mi] = m_run;
    Ll[mi] = l_run;
  }
  float* const ob = kb ? Op1 : Op0;
#pragma unroll
  for (int dc = 0; dc < 4; dc++)
#pragma unroll
    for (int r = 0; r < 4; r++)
      ob[((size_t)(b * 2048 + q0 + quad * 4 + r)) * 1024 + g * 64 + dc * 16 + n16] = o[dc][r];
}

// merge the two k-halves: O = (O0*2^(m0-m) + O1*2^(m1-m)) / (l0*2^(m0-m)+l1*2^(m1-m))
__global__ __launch_bounds__(256) void merge_halves(
    const float* __restrict__ Op0, const float* __restrict__ Op1,
    const float* __restrict__ Mm, const float* __restrict__ Ll,
    unsigned short* __restrict__ Obuf)
{
  const int i = blockIdx.x * 256 + threadIdx.x;   // 0..524287, 8 elems each
  const size_t e8 = (size_t)i * 8;
  const int e = (int)(e8 & 1023);
  const int q = (int)((e8 >> 10) & 2047);
  const int b = (int)(e8 >> 21);
  const int h = e >> 6;
  const size_t row = (size_t)b * 2048 + q;
  const size_t mi = ((size_t)b * 16 + h) * 2048 + q;
  const float m0 = Mm[mi], m1 = Mm[2 * 16 * 2048 + mi];
  const float l0 = Ll[mi], l1 = Ll[2 * 16 * 2048 + mi];
  const float m = fmaxf(m0, m1);
  const float w0 = exp2f(m0 - m), w1 = exp2f(m1 - m);
  const float inv = 1.0f / (l0 * w0 + l1 * w1);
  const float s0 = w0 * inv, s1 = w1 * inv;
  const float* pa = Op0 + row * 1024 + e;
  const float* pb = Op1 + row * 1024 + e;
  f32x4_t a0 = *(const f32x4_t*)pa, a1 = *(const f32x4_t*)(pa + 4);
  f32x4_t b0 = *(const f32x4_t*)pb, b1 = *(const f32x4_t*)(pb + 4);
  bf16x8_t o8;
#pragma unroll
  for (int j = 0; j < 4; j++) o8[j] = (short)f2bf(a0[j] * s0 + b0[j] * s1);
#pragma unroll
  for (int j = 0; j < 4; j++) o8[4 + j] = (short)f2bf(a1[j] * s0 + b1[j] * s1);
  *(bf16x8_t*)&Obuf[row * 1024 + e] = o8;
}

extern "C" void kernel_launch(void* const* d_in, const int* in_sizes, int n_in,
                              void* d_out, int out_size, void* d_ws, size_t ws_size,
                              hipStream_t stream) {
  const float* query = (const float*)d_in[0];
  const float* key   = (const float*)d_in[1];
  const float* value = (const float*)d_in[2];
  const float* Wq = (const float*)d_in[3];
  const float* bq = (const float*)d_in[4];
  const float* Wk = (const float*)d_in[5];
  const float* bk = (const float*)d_in[6];
  const float* Wv = (const float*)d_in[7];
  const float* bv = (const float*)d_in[8];
  const float* Wc = (const float*)d_in[9];
  // d_in[10] = bc: constant along softmax axis -> provably no effect on output
  const float* Wo = (const float*)d_in[11];
  const float* bo = (const float*)d_in[12];

  char* ws = (char*)d_ws;
  const size_t MB = 1024 * 1024;
  unsigned short* q_bf  = (unsigned short*)(ws);            // 8MB; later reused as Obuf
  unsigned short* k_bf  = (unsigned short*)(ws + 8 * MB);   // 8MB; later reused as VT
  unsigned short* v_bf  = (unsigned short*)(ws + 16 * MB);  // 8MB
  unsigned short* wq_bf = (unsigned short*)(ws + 24 * MB);  // 2MB
  unsigned short* wk_bf = (unsigned short*)(ws + 26 * MB);  // 2MB
  unsigned short* wv_bf = (unsigned short*)(ws + 28 * MB);  // 2MB
  unsigned short* wo_bf = (unsigned short*)(ws + 30 * MB);  // 2MB
  unsigned short* Qb    = (unsigned short*)(ws + 32 * MB);  // 8MB
  unsigned short* Kb    = (unsigned short*)(ws + 40 * MB);  // 8MB
  unsigned short* Vb    = (unsigned short*)(ws + 48 * MB);  // 8MB
  float* Op0 = (float*)(ws + 56 * MB);                      // 16MB f32 partial (kb=0)
  float* Mm  = (float*)(ws + 72 * MB);                      // 512KB
  float* Ll  = (float*)(ws + 72 * MB + 512 * 1024);         // 512KB (total 73MB)
  float* Op1 = (float*)d_out;                               // 16MB, dead until final GEMM
  unsigned short* VT   = k_bf;   // k_bf dead after K-projection
  unsigned short* Obuf = q_bf;   // q_bf dead after Q-projection

  ConvArgs ca;
  ca.src[0] = query; ca.dst[0] = q_bf;  ca.n[0] = 2 * 2048 * 1024;
  ca.src[1] = key;   ca.dst[1] = k_bf;  ca.n[1] = 2 * 2048 * 1024;
  ca.src[2] = value; ca.dst[2] = v_bf;  ca.n[2] = 2 * 2048 * 1024;
  ca.src[3] = Wq;    ca.dst[3] = wq_bf; ca.n[3] = 1024 * 1024;
  ca.src[4] = Wk;    ca.dst[4] = wk_bf; ca.n[4] = 1024 * 1024;
  ca.src[5] = Wv;    ca.dst[5] = wv_bf; ca.n[5] = 1024 * 1024;
  ca.src[6] = Wo;    ca.dst[6] = wo_bf; ca.n[6] = 1024 * 1024;
  convert_f32_bf16<<<dim3(2048, 7), 256, 0, stream>>>(ca);

  gemm_bt<<<dim3(32, 8), 256, 0, stream>>>(q_bf, wq_bf, bq, Qb, 4096, 1024, 1024, 0);
  gemm_bt<<<dim3(32, 8), 256, 0, stream>>>(k_bf, wk_bf, bk, Kb, 4096, 1024, 1024, 0);
  gemm_bt<<<dim3(32, 8), 256, 0, stream>>>(v_bf, wv_bf, bv, Vb, 4096, 1024, 1024, 0);

  transpose_v<<<dim3(32, 16, 2), 256, 0, stream>>>(Vb, VT);

  attention_fused<<<dim3(512), 1024, 0, stream>>>(Qb, Kb, VT, Wc, Op0, Op1, Mm, Ll);

  merge_halves<<<dim3(2048), 256, 0, stream>>>(Op0, Op1, Mm, Ll, Obuf);

  gemm_bt<<<dim3(32, 8), 256, 0, stream>>>(Obuf, wo_bf, bo, d_out, 4096, 1024, 1024, 1);
}

// Round 3
// 460.591 us; speedup vs baseline: 1.4577x; 1.4577x over previous
//
#include <hip/hip_runtime.h>

// Problem constants: B=2, S=2048, E=1024, H=16, DH=64. All fp32 in/out.
// Pipeline:
//   1) convert q,k,v,Wq,Wk,Wv,Wo fp32->bf16              (1 launch)
//   2) Q = q @ Wq^T + bq  (bf16 NT-GEMM, 128x128 tile)   (3 launches)
//   3) V^T reshape [b][h][d][s] for PV B-fragments       (1 launch)
//   4) fused attention with cross-head logit mixing      (1 launch)
//      S'_g = sum_h M~[g,h] * (Q_h K_h^T), M~ = (I+Wc)*(log2e/8); bc dropped
//      (constant along k => softmax-invariant). exp2-domain online softmax.
//      v4: single barrier per k-tile via double-buffered sraw/pbuf 3-stage
//      pipeline: PV(t-1) || mix/softmax/pack(t) || QK(t+1) between barriers.
//      Swapped mix-MFMA keeps softmax rows lane-local (2 shfls, 9 exp2,
//      scalar m/l state, 0-shfl cvt_pk P pack). No k-split (v3 spilled:
//      1024-thread block caps VGPR at 128; 64-reg co-residency infeasible).
//   5) out = O @ Wo^T + bo, fp32 to d_out                (1 launch)
// Workspace layout (56 MB total, reuse: O overlays q_bf, VT overlays k_bf).

typedef __attribute__((ext_vector_type(8))) short bf16x8_t;   // 8 bf16 (4 VGPRs)
typedef __attribute__((ext_vector_type(4))) short bf16x4_t;   // 4 bf16 (2 VGPRs)
typedef __attribute__((ext_vector_type(4))) float f32x4_t;    // MFMA accumulator

__device__ inline unsigned short f2bf(float f) {
  unsigned u = __builtin_bit_cast(unsigned, f);
  u += 0x7fffu + ((u >> 16) & 1u);          // round-to-nearest-even
  return (unsigned short)(u >> 16);
}

struct ConvArgs {
  const float* src[7];
  unsigned short* dst[7];
  int n[7];
};

__global__ __launch_bounds__(256) void convert_f32_bf16(ConvArgs a) {
  const int which = blockIdx.y;
  const int i = (blockIdx.x * 256 + threadIdx.x) * 8;
  if (i >= a.n[which]) return;
  const float* s = a.src[which] + i;
  f32x4_t x0 = *(const f32x4_t*)(s);
  f32x4_t x1 = *(const f32x4_t*)(s + 4);
  bf16x8_t o;
#pragma unroll
  for (int j = 0; j < 4; j++) o[j] = (short)f2bf(x0[j]);
#pragma unroll
  for (int j = 0; j < 4; j++) o[4 + j] = (short)f2bf(x1[j]);
  *(bf16x8_t*)(a.dst[which] + i) = o;
}

// C[m][n] = sum_k A[m][k] * Bt[n][k] + bias[n].  M,N,K multiples of 128/128/32.
// 256 threads = 4 waves in 2x2; wave tile 64x64 = 4x4 frags of 16x16; BK=32.
__global__ __launch_bounds__(256) void gemm_bt(
    const unsigned short* __restrict__ A, const unsigned short* __restrict__ Bt,
    const float* __restrict__ bias, void* __restrict__ C,
    int M, int N, int K, int c_is_f32)
{
  __shared__ unsigned short As[128 * 32];
  __shared__ unsigned short Bs[128 * 32];
  const int t = threadIdx.x;
  const int l = t & 63;
  const int w = t >> 6;
  const int quad = l >> 4, n16 = l & 15;
  const int wm = (w & 1) * 64, wn = (w >> 1) * 64;
  const long m0 = (long)blockIdx.x * 128, n0 = (long)blockIdx.y * 128;

  f32x4_t acc[4][4] = {};

  // staging: thread t covers tile row t/4 (+64 on round 1), cols (t%4)*8..+7
  const unsigned short* gA = A + (m0 + (t >> 2)) * (long)K + (t & 3) * 8;
  const unsigned short* gB = Bt + (n0 + (t >> 2)) * (long)K + (t & 3) * 8;
  const long rowskip = 64l * K;

  for (int kt = 0; kt < K; kt += 32) {
    bf16x8_t ra0 = *(const bf16x8_t*)(gA + kt);
    bf16x8_t ra1 = *(const bf16x8_t*)(gA + kt + rowskip);
    bf16x8_t rb0 = *(const bf16x8_t*)(gB + kt);
    bf16x8_t rb1 = *(const bf16x8_t*)(gB + kt + rowskip);
    __syncthreads();                       // protect LDS from prior iter reads
    *(bf16x8_t*)&As[t * 8] = ra0;          // elem (t>>2)*32 + (t&3)*8 == t*8
    *(bf16x8_t*)&As[2048 + t * 8] = ra1;
    *(bf16x8_t*)&Bs[t * 8] = rb0;
    *(bf16x8_t*)&Bs[2048 + t * 8] = rb1;
    __syncthreads();                       // staging visible
    bf16x8_t af[4], bfr[4];
#pragma unroll
    for (int i = 0; i < 4; i++) {
      af[i]  = *(const bf16x8_t*)&As[(wm + i * 16 + n16) * 32 + quad * 8];
      bfr[i] = *(const bf16x8_t*)&Bs[(wn + i * 16 + n16) * 32 + quad * 8];
    }
#pragma unroll
    for (int mi = 0; mi < 4; mi++)
#pragma unroll
      for (int ni = 0; ni < 4; ni++)
        acc[mi][ni] = __builtin_amdgcn_mfma_f32_16x16x32_bf16(af[mi], bfr[ni], acc[mi][ni], 0, 0, 0);
  }

#pragma unroll
  for (int ni = 0; ni < 4; ni++) {
    const long n = n0 + wn + ni * 16 + n16;
    const float bv = bias[n];
#pragma unroll
    for (int mi = 0; mi < 4; mi++) {
#pragma unroll
      for (int r = 0; r < 4; r++) {
        const long m = m0 + wm + mi * 16 + quad * 4 + r;  // D: row=(l>>4)*4+reg, col=l&15
        const float v = acc[mi][ni][r] + bv;
        if (c_is_f32) ((float*)C)[m * N + n] = v;
        else ((unsigned short*)C)[m * N + n] = f2bf(v);
      }
    }
  }
}

// V [b][s][h*64+d] -> VT [b][h][d][s]
__global__ __launch_bounds__(256) void transpose_v(
    const unsigned short* __restrict__ V, unsigned short* __restrict__ VT)
{
  __shared__ unsigned short tile[64][72];   // +8 pad
  const int t = threadIdx.x;
  const int s0 = blockIdx.x * 64, h = blockIdx.y, b = blockIdx.z;
#pragma unroll
  for (int r = 0; r < 2; r++) {
    const int elem = r * 2048 + t * 8;
    const int s = elem >> 6, d = elem & 63;
    *(bf16x8_t*)&tile[s][d] =
        *(const bf16x8_t*)&V[(size_t)(b * 2048 + s0 + s) * 1024 + h * 64 + d];
  }
  __syncthreads();
#pragma unroll
  for (int r = 0; r < 2; r++) {
    const int elem = r * 2048 + t * 8;
    const int d = elem >> 6, sl = elem & 63;
    bf16x8_t o;
#pragma unroll
    for (int j = 0; j < 8; j++) o[j] = (short)tile[sl + j][d];
    *(bf16x8_t*)&VT[((size_t)(b * 16 + h) * 64 + d) * 2048 + s0 + sl] = o;
  }
}

// Fused attention v4. Grid 256 (1-D, XCD-decoded). 1024 threads = 16 waves,
// wave g: QK^T + PV for head g; lane-local softmax row (h=n16, q=g) via
// swapped mix-MFMA. Double-buffered sraw/pbuf, ONE barrier per k-tile:
//   iter i: PV(i-1)[pbuf/alpha parity i-1] || mix/softmax/pack(i)[sraw parity
//   i -> pbuf parity i] || QK(i+1)[sraw parity i+1] -> __syncthreads.
// All cross-iteration RAW and WAR hazards are covered by the single barrier
// (write/read parities are disjoint within each interval).
__global__ __launch_bounds__(1024, 4) void attention_fused(
    const unsigned short* __restrict__ Qb, const unsigned short* __restrict__ Kb,
    const unsigned short* __restrict__ VT, const float* __restrict__ Wc,
    unsigned short* __restrict__ Obuf)
{
  __shared__ unsigned short sraw[2][512 * 36];  // [col=q*32+k][slot 0..31(+4)] 2x36864 B
  __shared__ unsigned short pbuf[2][16 * 580];  // [h]{q*36 + k}                2x18560 B
  __shared__ float alphabuf[2][16 * 17];        // [h][q] stride 17             2x1088 B
  __shared__ float lbuf[16 * 17];               // [h][q]                       1088 B
  __shared__ unsigned short mmat[256];          // M~[g_out][h] row-major       512 B

  const int t = threadIdx.x;
  const int g = t >> 6, l = t & 63;
  const int quad = l >> 4, n16 = l & 15;

  // XCD decode: id&7 = XCD; batch pinned to an XCD half
  const int id = blockIdx.x;
  const int xcd = id & 7;
  const int b = xcd >> 2;
  const int qb = (xcd & 3) * 32 + (id >> 3);
  const int q0 = qb * 16;

  // zero both sraw buffers once: mix A-operand reads the never-written slot
  // half (h>=16 region after XOR) which must be 0, not garbage.
  for (int i = t; i < 2 * 512 * 36; i += 1024) (&sraw[0][0])[i] = 0;
  if (t < 256) {
    // M~ = (I + Wc) * (log2e / 8): exp2-domain logits (v_exp_f32 is 2^x)
    const float v = ((((t >> 4) == (t & 15)) ? 1.0f : 0.0f) + Wc[t]) * 0.1803368801111204f;
    mmat[t] = f2bf(v);
  }
  __syncthreads();

  // mix B-frag: B[k=h=quad*8+j][n=g_out=n16]; zero for h>=16
  bf16x8_t mfrag;
  if (quad < 2) mfrag = *(const bf16x8_t*)&mmat[n16 * 16 + quad * 8];
  else { bf16x8_t z = {0, 0, 0, 0, 0, 0, 0, 0}; mfrag = z; }
  const int c7 = g >> 2;                     // col>>7 for this wave's mix chunks

  // Q A-frags: A[m=q=n16][k=d]
  bf16x8_t qf[2];
#pragma unroll
  for (int dr = 0; dr < 2; dr++)
    qf[dr] = *(const bf16x8_t*)&Qb[(size_t)(b * 2048 + q0 + n16) * 1024 + g * 64 + dr * 32 + quad * 8];

  const int slot = g ^ (quad << 3);          // sraw h-slot (writer quad == col>>7)
  const unsigned short* kptr = Kb + (size_t)(b * 2048 + n16) * 1024 + g * 64 + quad * 8;
  const unsigned short* vptr = VT + ((size_t)(b * 16 + g) * 64 + n16) * 2048 + quad * 8;

  bf16x8_t kf[2][2], vf[4];
  auto load_kf = [&](int kt) {
#pragma unroll
    for (int kc = 0; kc < 2; kc++)
#pragma unroll
      for (int dr = 0; dr < 2; dr++)
        kf[kc][dr] = *(const bf16x8_t*)(kptr + (size_t)(kt + kc * 16) * 1024 + dr * 32);
  };
  auto load_vf = [&](int kt) {
#pragma unroll
    for (int dc = 0; dc < 4; dc++)
      vf[dc] = *(const bf16x8_t*)(vptr + (size_t)dc * 16 * 2048 + kt);
  };
  auto qk_stage = [&](unsigned short* dst) {
    f32x4_t sf[2] = {};
#pragma unroll
    for (int kc = 0; kc < 2; kc++)
#pragma unroll
      for (int dr = 0; dr < 2; dr++)
        sf[kc] = __builtin_amdgcn_mfma_f32_16x16x32_bf16(qf[dr], kf[kc][dr], sf[kc], 0, 0, 0);
    // D: row=q=quad*4+r, col=key=kc*16+n16 -> dst[col=q*32+k][slot]
#pragma unroll
    for (int kc = 0; kc < 2; kc++)
#pragma unroll
      for (int r = 0; r < 4; r++)
        dst[((quad * 4 + r) * 32 + kc * 16 + n16) * 36 + slot] = f2bf(sf[kc][r]);
  };

  // prologue: QK(0) -> sraw[0]; prefetch K(1)
  load_kf(0);
  qk_stage(&sraw[0][0]);
  load_kf(32);
  __syncthreads();                            // sraw[0] visible

  f32x4_t o[4] = {};
  float m_run = -1e30f, l_run = 0.0f;

  for (int it = 0; it < 64; ++it) {
    const int cur = it & 1;
    const int oth = cur ^ 1;                  // parity of both (it-1) and (it+1)

    // ---- PV(it-1): rescale + accumulate (reads parity oth) ----
    if (it > 0) {
#pragma unroll
      for (int r = 0; r < 4; r++) {
        const float ar = alphabuf[oth][g * 17 + quad * 4 + r];
#pragma unroll
        for (int dc = 0; dc < 4; dc++) o[dc][r] *= ar;
      }
      const unsigned short* pp = &pbuf[oth][g * 580 + n16 * 36 + quad * 8];
      bf16x4_t plo = *(const bf16x4_t*)pp;
      bf16x4_t phi = *(const bf16x4_t*)(pp + 4);
      bf16x8_t pf = {plo[0], plo[1], plo[2], plo[3], phi[0], phi[1], phi[2], phi[3]};
#pragma unroll
      for (int dc = 0; dc < 4; dc++)
        o[dc] = __builtin_amdgcn_mfma_f32_16x16x32_bf16(pf, vf[dc], o[dc], 0, 0, 0);
    }
    // ---- issue V(it) global loads (consumed by PV(it) next interval) ----
    load_vf(it * 32);

    // ---- head mix (swapped): D[key][g_out] from sraw[cur] ----
    f32x4_t mixd[2];
#pragma unroll
    for (int c2 = 0; c2 < 2; c2++) {
      const int c = g * 2 + c2;               // cols [32g+16c2, +16): q=g
      const unsigned short* sp = &sraw[cur][(c * 16 + n16) * 36 + ((quad ^ c7) << 3)];
      bf16x4_t lo = *(const bf16x4_t*)sp;     // A[m=key=n16][k=h=quad*8+j]
      bf16x4_t hi = *(const bf16x4_t*)(sp + 4);
      bf16x8_t aa = {lo[0], lo[1], lo[2], lo[3], hi[0], hi[1], hi[2], hi[3]};
      f32x4_t z = {};
      mixd[c2] = __builtin_amdgcn_mfma_f32_16x16x32_bf16(aa, mfrag, z, 0, 0, 0);
    }
    // lane holds S'[h=n16][q=g][key = c2*16 + quad*4 + r] (log2 domain)

    // ---- lane-local online softmax (state replicated across quad lanes) ----
    float mx = fmaxf(fmaxf(fmaxf(mixd[0][0], mixd[0][1]), fmaxf(mixd[0][2], mixd[0][3])),
                     fmaxf(fmaxf(mixd[1][0], mixd[1][1]), fmaxf(mixd[1][2], mixd[1][3])));
    mx = fmaxf(mx, __shfl_xor(mx, 16));
    mx = fmaxf(mx, __shfl_xor(mx, 32));
    const float mnew = fmaxf(m_run, mx);
    const float alpha = exp2f(m_run - mnew);
    m_run = mnew;
    float p[2][4];
    float lsum = 0.0f;
#pragma unroll
    for (int c2 = 0; c2 < 2; c2++)
#pragma unroll
      for (int r = 0; r < 4; r++) {
        p[c2][r] = exp2f(mixd[c2][r] - mnew);
        lsum += p[c2][r];
      }
    l_run = l_run * alpha + lsum;             // lane-partial l; reduced at end

    // ---- pack P pairs in-register, write pbuf[cur] ----
    const int pbase = n16 * 580 + g * 36 + quad * 4;
#pragma unroll
    for (int c2 = 0; c2 < 2; c2++)
#pragma unroll
      for (int rp = 0; rp < 2; rp++) {
        unsigned pk;
        asm volatile("v_cvt_pk_bf16_f32 %0, %1, %2"
                     : "=v"(pk) : "v"(p[c2][2 * rp]), "v"(p[c2][2 * rp + 1]));
        *(unsigned*)&pbuf[cur][pbase + c2 * 16 + 2 * rp] = pk;
      }
    if (quad == 0) alphabuf[cur][n16 * 17 + g] = alpha;

    // ---- QK(it+1) -> sraw[oth]; prefetch K(it+2) ----
    if (it < 63) qk_stage(&sraw[oth][0]);
    if (it < 62) load_kf((it + 2) * 32);

    __syncthreads();  // publishes: pbuf/alpha[cur], sraw[oth]; retires all reads
  }

  // ---- epilogue: PV(63) (parity 1), l-reduce, normalize, store ----
  {
#pragma unroll
    for (int r = 0; r < 4; r++) {
      const float ar = alphabuf[1][g * 17 + quad * 4 + r];
#pragma unroll
      for (int dc = 0; dc < 4; dc++) o[dc][r] *= ar;
    }
    const unsigned short* pp = &pbuf[1][g * 580 + n16 * 36 + quad * 8];
    bf16x4_t plo = *(const bf16x4_t*)pp;
    bf16x4_t phi = *(const bf16x4_t*)(pp + 4);
    bf16x8_t pf = {plo[0], plo[1], plo[2], plo[3], phi[0], phi[1], phi[2], phi[3]};
#pragma unroll
    for (int dc = 0; dc < 4; dc++)
      o[dc] = __builtin_amdgcn_mfma_f32_16x16x32_bf16(pf, vf[dc], o[dc], 0, 0, 0);
  }

  l_run += __shfl_xor(l_run, 16);
  l_run += __shfl_xor(l_run, 32);
  if (quad == 0) lbuf[n16 * 17 + g] = l_run;   // l for row (h=n16, q=g)
  __syncthreads();
  float linv[4];
#pragma unroll
  for (int r = 0; r < 4; r++) linv[r] = 1.0f / lbuf[g * 17 + quad * 4 + r];
#pragma unroll
  for (int dc = 0; dc < 4; dc++)
#pragma unroll
    for (int r = 0; r < 4; r++) {
      const float v = o[dc][r] * linv[r];
      Obuf[(size_t)(b * 2048 + q0 + quad * 4 + r) * 1024 + g * 64 + dc * 16 + n16] = f2bf(v);
    }
}

extern "C" void kernel_launch(void* const* d_in, const int* in_sizes, int n_in,
                              void* d_out, int out_size, void* d_ws, size_t ws_size,
                              hipStream_t stream) {
  const float* query = (const float*)d_in[0];
  const float* key   = (const float*)d_in[1];
  const float* value = (const float*)d_in[2];
  const float* Wq = (const float*)d_in[3];
  const float* bq = (const float*)d_in[4];
  const float* Wk = (const float*)d_in[5];
  const float* bk = (const float*)d_in[6];
  const float* Wv = (const float*)d_in[7];
  const float* bv = (const float*)d_in[8];
  const float* Wc = (const float*)d_in[9];
  // d_in[10] = bc: constant along softmax axis -> provably no effect on output
  const float* Wo = (const float*)d_in[11];
  const float* bo = (const float*)d_in[12];

  char* ws = (char*)d_ws;
  const size_t MB = 1024 * 1024;
  unsigned short* q_bf  = (unsigned short*)(ws);            // 8MB; later reused as Obuf
  unsigned short* k_bf  = (unsigned short*)(ws + 8 * MB);   // 8MB; later reused as VT
  unsigned short* v_bf  = (unsigned short*)(ws + 16 * MB);  // 8MB
  unsigned short* wq_bf = (unsigned short*)(ws + 24 * MB);  // 2MB
  unsigned short* wk_bf = (unsigned short*)(ws + 26 * MB);  // 2MB
  unsigned short* wv_bf = (unsigned short*)(ws + 28 * MB);  // 2MB
  unsigned short* wo_bf = (unsigned short*)(ws + 30 * MB);  // 2MB
  unsigned short* Qb    = (unsigned short*)(ws + 32 * MB);  // 8MB
  unsigned short* Kb    = (unsigned short*)(ws + 40 * MB);  // 8MB
  unsigned short* Vb    = (unsigned short*)(ws + 48 * MB);  // 8MB  (total 56MB)
  unsigned short* VT   = k_bf;   // k_bf dead after K-projection
  unsigned short* Obuf = q_bf;   // q_bf dead after Q-projection

  ConvArgs ca;
  ca.src[0] = query; ca.dst[0] = q_bf;  ca.n[0] = 2 * 2048 * 1024;
  ca.src[1] = key;   ca.dst[1] = k_bf;  ca.n[1] = 2 * 2048 * 1024;
  ca.src[2] = value; ca.dst[2] = v_bf;  ca.n[2] = 2 * 2048 * 1024;
  ca.src[3] = Wq;    ca.dst[3] = wq_bf; ca.n[3] = 1024 * 1024;
  ca.src[4] = Wk;    ca.dst[4] = wk_bf; ca.n[4] = 1024 * 1024;
  ca.src[5] = Wv;    ca.dst[5] = wv_bf; ca.n[5] = 1024 * 1024;
  ca.src[6] = Wo;    ca.dst[6] = wo_bf; ca.n[6] = 1024 * 1024;
  convert_f32_bf16<<<dim3(2048, 7), 256, 0, stream>>>(ca);

  gemm_bt<<<dim3(32, 8), 256, 0, stream>>>(q_bf, wq_bf, bq, Qb, 4096, 1024, 1024, 0);
  gemm_bt<<<dim3(32, 8), 256, 0, stream>>>(k_bf, wk_bf, bk, Kb, 4096, 1024, 1024, 0);
  gemm_bt<<<dim3(32, 8), 256, 0, stream>>>(v_bf, wv_bf, bv, Vb, 4096, 1024, 1024, 0);

  transpose_v<<<dim3(32, 16, 2), 256, 0, stream>>>(Vb, VT);

  attention_fused<<<dim3(256), 1024, 0, stream>>>(Qb, Kb, VT, Wc, Obuf);

  gemm_bt<<<dim3(32, 8), 256, 0, stream>>>(Obuf, wo_bf, bo, d_out, 4096, 1024, 1024, 1);
}

// Round 4
// 458.610 us; speedup vs baseline: 1.4640x; 1.0043x over previous
//
#include <hip/hip_runtime.h>

// Problem constants: B=2, S=2048, E=1024, H=16, DH=64. All fp32 in/out.
// Pipeline:
//   1) convert q,k,v,Wq,Wk,Wv,Wo fp32->bf16              (1 launch)
//   2) Q = q @ Wq^T + bq  (bf16 NT-GEMM, 128x128 tile)   (3 launches)
//   3) V^T reshape [b][h][d][s] for PV B-fragments       (1 launch)
//   4) fused attention with cross-head logit mixing      (1 launch)
//      S'_g = sum_h M~[g,h] * (Q_h K_h^T), M~ = (I+Wc)*(log2e/8); bc dropped
//      (constant along k => softmax-invariant). exp2-domain online softmax.
//      v5: v4's 3-stage pipeline (PV(t-1) || mix/softmax(t) || QK(t+1),
//      double-buffered sraw/pbuf, one barrier per k-tile) BUT with raw
//      s_barrier + lgkmcnt(0)-only (no vmcnt drain): __syncthreads emits
//      s_waitcnt vmcnt(0) which was draining the kf/vf prefetches every
//      iteration -- the dominant ~6K idle cycles/interval across v1-v4.
//      LDS-only publication needs lgkmcnt(0); no cross-wave global comms
//      inside the kernel, so vmcnt may stay outstanding across barriers.
//   5) out = O @ Wo^T + bo, fp32 to d_out                (1 launch)
// Workspace layout (56 MB total, reuse: O overlays q_bf, VT overlays k_bf).

typedef __attribute__((ext_vector_type(8))) short bf16x8_t;   // 8 bf16 (4 VGPRs)
typedef __attribute__((ext_vector_type(4))) short bf16x4_t;   // 4 bf16 (2 VGPRs)
typedef __attribute__((ext_vector_type(4))) float f32x4_t;    // MFMA accumulator

__device__ inline unsigned short f2bf(float f) {
  unsigned u = __builtin_bit_cast(unsigned, f);
  u += 0x7fffu + ((u >> 16) & 1u);          // round-to-nearest-even
  return (unsigned short)(u >> 16);
}

// Barrier that publishes LDS (lgkmcnt) but lets global loads stay in flight
// across it (no vmcnt drain -- unlike __syncthreads). The compiler still
// auto-inserts precise vmcnt(N) waits before actual consumers of loads.
__device__ inline void bar_lds() {
  asm volatile("s_waitcnt lgkmcnt(0)" ::: "memory");
  __builtin_amdgcn_s_barrier();
}

struct ConvArgs {
  const float* src[7];
  unsigned short* dst[7];
  int n[7];
};

__global__ __launch_bounds__(256) void convert_f32_bf16(ConvArgs a) {
  const int which = blockIdx.y;
  const int i = (blockIdx.x * 256 + threadIdx.x) * 8;
  if (i >= a.n[which]) return;
  const float* s = a.src[which] + i;
  f32x4_t x0 = *(const f32x4_t*)(s);
  f32x4_t x1 = *(const f32x4_t*)(s + 4);
  bf16x8_t o;
#pragma unroll
  for (int j = 0; j < 4; j++) o[j] = (short)f2bf(x0[j]);
#pragma unroll
  for (int j = 0; j < 4; j++) o[4 + j] = (short)f2bf(x1[j]);
  *(bf16x8_t*)(a.dst[which] + i) = o;
}

// C[m][n] = sum_k A[m][k] * Bt[n][k] + bias[n].  M,N,K multiples of 128/128/32.
// 256 threads = 4 waves in 2x2; wave tile 64x64 = 4x4 frags of 16x16; BK=32.
// v5: next-tile register prefetch + raw barriers (loads in flight across
// both barriers and the MFMA block; consumed at next iter's ds_write).
__global__ __launch_bounds__(256) void gemm_bt(
    const unsigned short* __restrict__ A, const unsigned short* __restrict__ Bt,
    const float* __restrict__ bias, void* __restrict__ C,
    int M, int N, int K, int c_is_f32)
{
  __shared__ unsigned short As[128 * 32];
  __shared__ unsigned short Bs[128 * 32];
  const int t = threadIdx.x;
  const int l = t & 63;
  const int w = t >> 6;
  const int quad = l >> 4, n16 = l & 15;
  const int wm = (w & 1) * 64, wn = (w >> 1) * 64;
  const long m0 = (long)blockIdx.x * 128, n0 = (long)blockIdx.y * 128;

  f32x4_t acc[4][4] = {};

  // staging: thread t covers tile row t/4 (+64 on round 1), cols (t%4)*8..+7
  const unsigned short* gA = A + (m0 + (t >> 2)) * (long)K + (t & 3) * 8;
  const unsigned short* gB = Bt + (n0 + (t >> 2)) * (long)K + (t & 3) * 8;
  const long rowskip = 64l * K;

  bf16x8_t ra0 = *(const bf16x8_t*)(gA);
  bf16x8_t ra1 = *(const bf16x8_t*)(gA + rowskip);
  bf16x8_t rb0 = *(const bf16x8_t*)(gB);
  bf16x8_t rb1 = *(const bf16x8_t*)(gB + rowskip);

  for (int kt = 0; kt < K; kt += 32) {
    bf16x8_t na0, na1, nb0, nb1;
    if (kt + 32 < K) {                     // prefetch next tile (in flight
      na0 = *(const bf16x8_t*)(gA + kt + 32);            // across barriers)
      na1 = *(const bf16x8_t*)(gA + kt + 32 + rowskip);
      nb0 = *(const bf16x8_t*)(gB + kt + 32);
      nb1 = *(const bf16x8_t*)(gB + kt + 32 + rowskip);
    }
    bar_lds();                             // prior-iter LDS reads retired
    *(bf16x8_t*)&As[t * 8] = ra0;          // elem (t>>2)*32 + (t&3)*8 == t*8
    *(bf16x8_t*)&As[2048 + t * 8] = ra1;
    *(bf16x8_t*)&Bs[t * 8] = rb0;
    *(bf16x8_t*)&Bs[2048 + t * 8] = rb1;
    bar_lds();                             // staging visible
    bf16x8_t af[4], bfr[4];
#pragma unroll
    for (int i = 0; i < 4; i++) {
      af[i]  = *(const bf16x8_t*)&As[(wm + i * 16 + n16) * 32 + quad * 8];
      bfr[i] = *(const bf16x8_t*)&Bs[(wn + i * 16 + n16) * 32 + quad * 8];
    }
#pragma unroll
    for (int mi = 0; mi < 4; mi++)
#pragma unroll
      for (int ni = 0; ni < 4; ni++)
        acc[mi][ni] = __builtin_amdgcn_mfma_f32_16x16x32_bf16(af[mi], bfr[ni], acc[mi][ni], 0, 0, 0);
    ra0 = na0; ra1 = na1; rb0 = nb0; rb1 = nb1;
  }

#pragma unroll
  for (int ni = 0; ni < 4; ni++) {
    const long n = n0 + wn + ni * 16 + n16;
    const float bv = bias[n];
#pragma unroll
    for (int mi = 0; mi < 4; mi++) {
#pragma unroll
      for (int r = 0; r < 4; r++) {
        const long m = m0 + wm + mi * 16 + quad * 4 + r;  // D: row=(l>>4)*4+reg, col=l&15
        const float v = acc[mi][ni][r] + bv;
        if (c_is_f32) ((float*)C)[m * N + n] = v;
        else ((unsigned short*)C)[m * N + n] = f2bf(v);
      }
    }
  }
}

// V [b][s][h*64+d] -> VT [b][h][d][s]
__global__ __launch_bounds__(256) void transpose_v(
    const unsigned short* __restrict__ V, unsigned short* __restrict__ VT)
{
  __shared__ unsigned short tile[64][72];   // +8 pad
  const int t = threadIdx.x;
  const int s0 = blockIdx.x * 64, h = blockIdx.y, b = blockIdx.z;
#pragma unroll
  for (int r = 0; r < 2; r++) {
    const int elem = r * 2048 + t * 8;
    const int s = elem >> 6, d = elem & 63;
    *(bf16x8_t*)&tile[s][d] =
        *(const bf16x8_t*)&V[(size_t)(b * 2048 + s0 + s) * 1024 + h * 64 + d];
  }
  __syncthreads();
#pragma unroll
  for (int r = 0; r < 2; r++) {
    const int elem = r * 2048 + t * 8;
    const int d = elem >> 6, sl = elem & 63;
    bf16x8_t o;
#pragma unroll
    for (int j = 0; j < 8; j++) o[j] = (short)tile[sl + j][d];
    *(bf16x8_t*)&VT[((size_t)(b * 16 + h) * 64 + d) * 2048 + s0 + sl] = o;
  }
}

// Fused attention v5. Grid 256 (1-D, XCD-decoded). 1024 threads = 16 waves,
// wave g: QK^T + PV for head g; lane-local softmax row (h=n16, q=g) via
// swapped mix-MFMA. Double-buffered sraw/pbuf, ONE raw barrier per k-tile:
//   iter i: PV(i-1)[pbuf/alpha parity i-1] || mix/softmax/pack(i)[sraw parity
//   i -> pbuf parity i] || QK(i+1)[sraw parity i+1] -> bar_lds.
// bar_lds = lgkmcnt(0) + s_barrier: publishes/retires all LDS traffic (every
// cross-iteration RAW & WAR) but leaves kf/vf global prefetches in flight.
__global__ __launch_bounds__(1024, 4) void attention_fused(
    const unsigned short* __restrict__ Qb, const unsigned short* __restrict__ Kb,
    const unsigned short* __restrict__ VT, const float* __restrict__ Wc,
    unsigned short* __restrict__ Obuf)
{
  __shared__ unsigned short sraw[2][512 * 36];  // [col=q*32+k][slot 0..31(+4)] 2x36864 B
  __shared__ unsigned short pbuf[2][16 * 580];  // [h]{q*36 + k}                2x18560 B
  __shared__ float alphabuf[2][16 * 17];        // [h][q] stride 17             2x1088 B
  __shared__ float lbuf[16 * 17];               // [h][q]                       1088 B
  __shared__ unsigned short mmat[256];          // M~[g_out][h] row-major       512 B

  const int t = threadIdx.x;
  const int g = t >> 6, l = t & 63;
  const int quad = l >> 4, n16 = l & 15;

  // XCD decode: id&7 = XCD; batch pinned to an XCD half
  const int id = blockIdx.x;
  const int xcd = id & 7;
  const int b = xcd >> 2;
  const int qb = (xcd & 3) * 32 + (id >> 3);
  const int q0 = qb * 16;

  // zero both sraw buffers once: mix A-operand reads the never-written slot
  // half (h>=16 region after XOR) which must be 0, not garbage.
  for (int i = t; i < 2 * 512 * 36; i += 1024) (&sraw[0][0])[i] = 0;
  if (t < 256) {
    // M~ = (I + Wc) * (log2e / 8): exp2-domain logits (v_exp_f32 is 2^x)
    const float v = ((((t >> 4) == (t & 15)) ? 1.0f : 0.0f) + Wc[t]) * 0.1803368801111204f;
    mmat[t] = f2bf(v);
  }
  __syncthreads();

  // mix B-frag: B[k=h=quad*8+j][n=g_out=n16]; zero for h>=16
  bf16x8_t mfrag;
  if (quad < 2) mfrag = *(const bf16x8_t*)&mmat[n16 * 16 + quad * 8];
  else { bf16x8_t z = {0, 0, 0, 0, 0, 0, 0, 0}; mfrag = z; }
  const int c7 = g >> 2;                     // col>>7 for this wave's mix chunks

  // Q A-frags: A[m=q=n16][k=d]
  bf16x8_t qf[2];
#pragma unroll
  for (int dr = 0; dr < 2; dr++)
    qf[dr] = *(const bf16x8_t*)&Qb[(size_t)(b * 2048 + q0 + n16) * 1024 + g * 64 + dr * 32 + quad * 8];

  const int slot = g ^ (quad << 3);          // sraw h-slot (writer quad == col>>7)
  const unsigned short* kptr = Kb + (size_t)(b * 2048 + n16) * 1024 + g * 64 + quad * 8;
  const unsigned short* vptr = VT + ((size_t)(b * 16 + g) * 64 + n16) * 2048 + quad * 8;

  bf16x8_t kf[2][2], vf[4];
  auto load_kf = [&](int kt) {
#pragma unroll
    for (int kc = 0; kc < 2; kc++)
#pragma unroll
      for (int dr = 0; dr < 2; dr++)
        kf[kc][dr] = *(const bf16x8_t*)(kptr + (size_t)(kt + kc * 16) * 1024 + dr * 32);
  };
  auto load_vf = [&](int kt) {
#pragma unroll
    for (int dc = 0; dc < 4; dc++)
      vf[dc] = *(const bf16x8_t*)(vptr + (size_t)dc * 16 * 2048 + kt);
  };
  auto qk_stage = [&](unsigned short* dst) {
    f32x4_t sf[2] = {};
#pragma unroll
    for (int kc = 0; kc < 2; kc++)
#pragma unroll
      for (int dr = 0; dr < 2; dr++)
        sf[kc] = __builtin_amdgcn_mfma_f32_16x16x32_bf16(qf[dr], kf[kc][dr], sf[kc], 0, 0, 0);
    // D: row=q=quad*4+r, col=key=kc*16+n16 -> dst[col=q*32+k][slot]
#pragma unroll
    for (int kc = 0; kc < 2; kc++)
#pragma unroll
      for (int r = 0; r < 4; r++)
        dst[((quad * 4 + r) * 32 + kc * 16 + n16) * 36 + slot] = f2bf(sf[kc][r]);
  };

  // prologue: QK(0) -> sraw[0]; prefetch K(1)
  load_kf(0);
  qk_stage(&sraw[0][0]);
  load_kf(32);
  bar_lds();                                  // sraw[0] visible; K(1) in flight

  f32x4_t o[4] = {};
  float m_run = -1e30f, l_run = 0.0f;

  for (int it = 0; it < 64; ++it) {
    const int cur = it & 1;
    const int oth = cur ^ 1;                  // parity of both (it-1) and (it+1)

    // ---- PV(it-1): rescale + accumulate (reads parity oth) ----
    if (it > 0) {
#pragma unroll
      for (int r = 0; r < 4; r++) {
        const float ar = alphabuf[oth][g * 17 + quad * 4 + r];
#pragma unroll
        for (int dc = 0; dc < 4; dc++) o[dc][r] *= ar;
      }
      const unsigned short* pp = &pbuf[oth][g * 580 + n16 * 36 + quad * 8];
      bf16x4_t plo = *(const bf16x4_t*)pp;
      bf16x4_t phi = *(const bf16x4_t*)(pp + 4);
      bf16x8_t pf = {plo[0], plo[1], plo[2], plo[3], phi[0], phi[1], phi[2], phi[3]};
#pragma unroll
      for (int dc = 0; dc < 4; dc++)
        o[dc] = __builtin_amdgcn_mfma_f32_16x16x32_bf16(pf, vf[dc], o[dc], 0, 0, 0);
    }
    // ---- issue V(it) global loads (consumed by PV(it) next interval) ----
    load_vf(it * 32);

    // ---- head mix (swapped): D[key][g_out] from sraw[cur] ----
    f32x4_t mixd[2];
#pragma unroll
    for (int c2 = 0; c2 < 2; c2++) {
      const int c = g * 2 + c2;               // cols [32g+16c2, +16): q=g
      const unsigned short* sp = &sraw[cur][(c * 16 + n16) * 36 + ((quad ^ c7) << 3)];
      bf16x4_t lo = *(const bf16x4_t*)sp;     // A[m=key=n16][k=h=quad*8+j]
      bf16x4_t hi = *(const bf16x4_t*)(sp + 4);
      bf16x8_t aa = {lo[0], lo[1], lo[2], lo[3], hi[0], hi[1], hi[2], hi[3]};
      f32x4_t z = {};
      mixd[c2] = __builtin_amdgcn_mfma_f32_16x16x32_bf16(aa, mfrag, z, 0, 0, 0);
    }
    // lane holds S'[h=n16][q=g][key = c2*16 + quad*4 + r] (log2 domain)

    // ---- lane-local online softmax (state replicated across quad lanes) ----
    float mx = fmaxf(fmaxf(fmaxf(mixd[0][0], mixd[0][1]), fmaxf(mixd[0][2], mixd[0][3])),
                     fmaxf(fmaxf(mixd[1][0], mixd[1][1]), fmaxf(mixd[1][2], mixd[1][3])));
    mx = fmaxf(mx, __shfl_xor(mx, 16));
    mx = fmaxf(mx, __shfl_xor(mx, 32));
    const float mnew = fmaxf(m_run, mx);
    const float alpha = exp2f(m_run - mnew);
    m_run = mnew;
    float p[2][4];
    float lsum = 0.0f;
#pragma unroll
    for (int c2 = 0; c2 < 2; c2++)
#pragma unroll
      for (int r = 0; r < 4; r++) {
        p[c2][r] = exp2f(mixd[c2][r] - mnew);
        lsum += p[c2][r];
      }
    l_run = l_run * alpha + lsum;             // lane-partial l; reduced at end

    // ---- pack P pairs in-register, write pbuf[cur] ----
    const int pbase = n16 * 580 + g * 36 + quad * 4;
#pragma unroll
    for (int c2 = 0; c2 < 2; c2++)
#pragma unroll
      for (int rp = 0; rp < 2; rp++) {
        unsigned pk;
        asm volatile("v_cvt_pk_bf16_f32 %0, %1, %2"
                     : "=v"(pk) : "v"(p[c2][2 * rp]), "v"(p[c2][2 * rp + 1]));
        *(unsigned*)&pbuf[cur][pbase + c2 * 16 + 2 * rp] = pk;
      }
    if (quad == 0) alphabuf[cur][n16 * 17 + g] = alpha;

    // ---- QK(it+1) -> sraw[oth]; prefetch K(it+2) ----
    if (it < 63) qk_stage(&sraw[oth][0]);
    if (it < 62) load_kf((it + 2) * 32);

    bar_lds();  // publishes pbuf/alpha[cur], sraw[oth]; retires all LDS reads;
                // kf/vf global loads remain in flight across the barrier
  }

  // ---- epilogue: PV(63) (parity 1), l-reduce, normalize, store ----
  {
#pragma unroll
    for (int r = 0; r < 4; r++) {
      const float ar = alphabuf[1][g * 17 + quad * 4 + r];
#pragma unroll
      for (int dc = 0; dc < 4; dc++) o[dc][r] *= ar;
    }
    const unsigned short* pp = &pbuf[1][g * 580 + n16 * 36 + quad * 8];
    bf16x4_t plo = *(const bf16x4_t*)pp;
    bf16x4_t phi = *(const bf16x4_t*)(pp + 4);
    bf16x8_t pf = {plo[0], plo[1], plo[2], plo[3], phi[0], phi[1], phi[2], phi[3]};
#pragma unroll
    for (int dc = 0; dc < 4; dc++)
      o[dc] = __builtin_amdgcn_mfma_f32_16x16x32_bf16(pf, vf[dc], o[dc], 0, 0, 0);
  }

  l_run += __shfl_xor(l_run, 16);
  l_run += __shfl_xor(l_run, 32);
  if (quad == 0) lbuf[n16 * 17 + g] = l_run;   // l for row (h=n16, q=g)
  bar_lds();
  float linv[4];
#pragma unroll
  for (int r = 0; r < 4; r++) linv[r] = 1.0f / lbuf[g * 17 + quad * 4 + r];
#pragma unroll
  for (int dc = 0; dc < 4; dc++)
#pragma unroll
    for (int r = 0; r < 4; r++) {
      const float v = o[dc][r] * linv[r];
      Obuf[(size_t)(b * 2048 + q0 + quad * 4 + r) * 1024 + g * 64 + dc * 16 + n16] = f2bf(v);
    }
}

extern "C" void kernel_launch(void* const* d_in, const int* in_sizes, int n_in,
                              void* d_out, int out_size, void* d_ws, size_t ws_size,
                              hipStream_t stream) {
  const float* query = (const float*)d_in[0];
  const float* key   = (const float*)d_in[1];
  const float* value = (const float*)d_in[2];
  const float* Wq = (const float*)d_in[3];
  const float* bq = (const float*)d_in[4];
  const float* Wk = (const float*)d_in[5];
  const float* bk = (const float*)d_in[6];
  const float* Wv = (const float*)d_in[7];
  const float* bv = (const float*)d_in[8];
  const float* Wc = (const float*)d_in[9];
  // d_in[10] = bc: constant along softmax axis -> provably no effect on output
  const float* Wo = (const float*)d_in[11];
  const float* bo = (const float*)d_in[12];

  char* ws = (char*)d_ws;
  const size_t MB = 1024 * 1024;
  unsigned short* q_bf  = (unsigned short*)(ws);            // 8MB; later reused as Obuf
  unsigned short* k_bf  = (unsigned short*)(ws + 8 * MB);   // 8MB; later reused as VT
  unsigned short* v_bf  = (unsigned short*)(ws + 16 * MB);  // 8MB
  unsigned short* wq_bf = (unsigned short*)(ws + 24 * MB);  // 2MB
  unsigned short* wk_bf = (unsigned short*)(ws + 26 * MB);  // 2MB
  unsigned short* wv_bf = (unsigned short*)(ws + 28 * MB);  // 2MB
  unsigned short* wo_bf = (unsigned short*)(ws + 30 * MB);  // 2MB
  unsigned short* Qb    = (unsigned short*)(ws + 32 * MB);  // 8MB
  unsigned short* Kb    = (unsigned short*)(ws + 40 * MB);  // 8MB
  unsigned short* Vb    = (unsigned short*)(ws + 48 * MB);  // 8MB  (total 56MB)
  unsigned short* VT   = k_bf;   // k_bf dead after K-projection
  unsigned short* Obuf = q_bf;   // q_bf dead after Q-projection

  ConvArgs ca;
  ca.src[0] = query; ca.dst[0] = q_bf;  ca.n[0] = 2 * 2048 * 1024;
  ca.src[1] = key;   ca.dst[1] = k_bf;  ca.n[1] = 2 * 2048 * 1024;
  ca.src[2] = value; ca.dst[2] = v_bf;  ca.n[2] = 2 * 2048 * 1024;
  ca.src[3] = Wq;    ca.dst[3] = wq_bf; ca.n[3] = 1024 * 1024;
  ca.src[4] = Wk;    ca.dst[4] = wk_bf; ca.n[4] = 1024 * 1024;
  ca.src[5] = Wv;    ca.dst[5] = wv_bf; ca.n[5] = 1024 * 1024;
  ca.src[6] = Wo;    ca.dst[6] = wo_bf; ca.n[6] = 1024 * 1024;
  convert_f32_bf16<<<dim3(2048, 7), 256, 0, stream>>>(ca);

  gemm_bt<<<dim3(32, 8), 256, 0, stream>>>(q_bf, wq_bf, bq, Qb, 4096, 1024, 1024, 0);
  gemm_bt<<<dim3(32, 8), 256, 0, stream>>>(k_bf, wk_bf, bk, Kb, 4096, 1024, 1024, 0);
  gemm_bt<<<dim3(32, 8), 256, 0, stream>>>(v_bf, wv_bf, bv, Vb, 4096, 1024, 1024, 0);

  transpose_v<<<dim3(32, 16, 2), 256, 0, stream>>>(Vb, VT);

  attention_fused<<<dim3(256), 1024, 0, stream>>>(Qb, Kb, VT, Wc, Obuf);

  gemm_bt<<<dim3(32, 8), 256, 0, stream>>>(Obuf, wo_bf, bo, d_out, 4096, 1024, 1024, 1);
}